// Round 10
// baseline (190.503 us; speedup 1.0000x reference)
//
#include <hip/hip_runtime.h>

#define BN 8192
#define DIM 512
#define TEMP 0.07f
#define NPART 12
#define NEGINF (-__builtin_inff())

typedef _Float16 half8 __attribute__((ext_vector_type(8)));
typedef float f32x4 __attribute__((ext_vector_type(4)));

// async 16B global->LDS (wave-uniform base + lane*16 on the LDS side)
#define GLOAD16(gp, lp) __builtin_amdgcn_global_load_lds( \
    (__attribute__((address_space(1))) const void*)(gp),  \
    (__attribute__((address_space(3))) void*)(lp), 16, 0, 0)

// branch-free sorted-desc top-5 insert: 5 x (max+min) = 10 VALU, no compares
__device__ __forceinline__ void ins5(float t5[5], float v) {
#pragma unroll
  for (int k = 0; k < 5; k++) {
    float hi = fmaxf(t5[k], v);
    v = fminf(t5[k], v);
    t5[k] = hi;
  }
}

// guarded LSE-merge of (m,s) with (mp,sp); s-terms are sums of exp((x-m)/TEMP)
// symmetric in FP: butterfly partners compute bit-identical results
__device__ __forceinline__ void lse_merge(float& m, float& s, float mp, float sp) {
  if (mp > m) {
    s = s * expf((m - mp) / TEMP) + sp;  // m=-inf -> 0*0, safe
    m = mp;
  } else if (sp > 0.f) {                 // sp==0 iff empty partial (mp=-inf)
    s += sp * expf((mp - m) / TEMP);
  }
}

// ---------- 1. L2-normalize fp32 rows -> fp16 matrix (one wave per row, row-major) ----------
__global__ __launch_bounds__(256) void k_normalize(const float* __restrict__ feat,
                                                   _Float16* __restrict__ f16,
                                                   unsigned* __restrict__ cells) {
  if (blockIdx.x == 0 && threadIdx.x == 0) {
    ((float*)cells)[1] = 0.0f;      // loss-sum accumulator
    cells[2] = 0u;                  // completion counter for k_final
  }
  int gid = blockIdx.x * 256 + threadIdx.x;
  int row = gid >> 6, lane = gid & 63;
  const float4* rp = (const float4*)(feat + (size_t)row * DIM);
  float4 v0 = rp[lane * 2];
  float4 v1 = rp[lane * 2 + 1];
  float ss = v0.x * v0.x + v0.y * v0.y + v0.z * v0.z + v0.w * v0.w +
             v1.x * v1.x + v1.y * v1.y + v1.z * v1.z + v1.w * v1.w;
#pragma unroll
  for (int m = 1; m < 64; m <<= 1) ss += __shfl_xor(ss, m, 64);
  float r = 1.0f / fmaxf(sqrtf(ss), 1e-12f);
  half8 o;
  o[0] = (_Float16)(v0.x * r); o[1] = (_Float16)(v0.y * r);
  o[2] = (_Float16)(v0.z * r); o[3] = (_Float16)(v0.w * r);
  o[4] = (_Float16)(v1.x * r); o[5] = (_Float16)(v1.y * r);
  o[6] = (_Float16)(v1.z * r); o[7] = (_Float16)(v1.w * r);
  ((half8*)(f16 + (size_t)row * DIM))[lane] = o;
}

// record store: t5[5], m, s, ps, cn packed as 3 float4 (12 floats, 48 B, 16-B aligned)
__device__ __forceinline__ void store_rec(float* d, const float t5[5], float m, float s,
                                          float ps, float cn) {
  *(float4*)d = make_float4(t5[0], t5[1], t5[2], t5[3]);
  *(float4*)(d + 4) = make_float4(t5[4], m, s, ps);
  *(float4*)(d + 8) = make_float4(cn, 0.f, 0.f, 0.f);
}

// ======================================================================
// Triangle GEMM: jobs = (bi,bj), bi<=bj. Off-diag jobs harvest BOTH sides
// of the symmetric sim tile. Record layout: toppart[(row*64 + slot)*12].
// launch_bounds(256,4): target 64 arch VGPR + 64 AGPR acc = 128 unified
// -> 4 waves/SIMD. Register diet vs R9: staging pointer arrays (16 VGPR)
// replaced by wave-uniform SGPR bases + one per-thread 32-bit offset.
// Spill signature to watch: WRITE_SIZE >> 33 MB.
// ======================================================================
__global__ __launch_bounds__(256, 4) void k_tri(const _Float16* __restrict__ f16,
                                                const int* __restrict__ idx,
                                                float* __restrict__ toppart) {
  __shared__ float Csm[64 * 129];          // 33,024 B; C half-tile (64 A-rows x 128 B-cols)
  _Float16* Asm = (_Float16*)Csm;          // staging alias: 128 rows x 8 granules x 8 halfs = 16 KB
  _Float16* Bsm = Asm + 128 * 64;          // next 16 KB

  int t = threadIdx.x;
  int w = t >> 6, lane = t & 63;
  int wr = w >> 1, wc = w & 1;
  int l15 = lane & 15, l4 = lane >> 4;

  // decode (bi,bj) from blockIdx: off(g) = g*64 - g*(g-1)/2
  int b = blockIdx.x;
  int bi = (int)(64.5f - sqrtf(64.5f * 64.5f - 2.0f * (float)b));
  bi = bi < 0 ? 0 : (bi > 63 ? 63 : bi);
  while (bi > 0 && (bi * 64 - (bi * (bi - 1)) / 2) > b) bi--;
  while (((bi + 1) * 64 - ((bi + 1) * bi) / 2) <= b) bi++;
  int bj = bi + (b - (bi * 64 - (bi * (bi - 1)) / 2));
  bool diag = (bi == bj);

  int swz = l15 & 7;   // fragment-read XOR swizzle (matches staging granule permutation)
  int jbase = bj * 128;
  f32x4 acc[4][4] = {};

  // staging addressing: wave-uniform SGPR bases + per-thread p-invariant offset.
  // u = p*256 + t; row = u>>3 = p*32 + (t>>3); cko = (t&7) ^ ((t>>3)&7)  (p-invariant)
  const _Float16* baseA = f16 + (size_t)bi * 128 * DIM;   // uniform -> SGPR
  const _Float16* baseB = f16 + (size_t)jbase * DIM;      // uniform -> SGPR
  int tr = t >> 3;
  int thrOff = tr * DIM + ((t & 7) ^ (tr & 7)) * 8;       // halfs, per-thread (1 VGPR)
  int ldsT = t * 8;                                        // halfs; +p*2048 const per p

  // ---- K-loop (R3 structure, proven) ----
  for (int kc = 0; kc < 8; kc++) {
    int k0 = kc * 64;
    __syncthreads();
#pragma unroll
    for (int p = 0; p < 4; p++) {
      int off = thrOff + p * (32 * DIM) + k0;
      GLOAD16(baseA + off, Asm + ldsT + p * 2048);
      GLOAD16(baseB + off, Bsm + ldsT + p * 2048);
    }
    __syncthreads();
#pragma unroll
    for (int s = 0; s < 2; s++) {
      half8 af[4], bf[4];
#pragma unroll
      for (int ti = 0; ti < 4; ti++) {
        int row = wr * 64 + ti * 16 + l15;
        af[ti] = *(const half8*)(Asm + (row * 8 + ((s * 4 + l4) ^ swz)) * 8);
      }
#pragma unroll
      for (int tj = 0; tj < 4; tj++) {
        int row = wc * 64 + tj * 16 + l15;
        bf[tj] = *(const half8*)(Bsm + (row * 8 + ((s * 4 + l4) ^ swz)) * 8);
      }
#pragma unroll
      for (int ti = 0; ti < 4; ti++)
#pragma unroll
        for (int tj = 0; tj < 4; tj++)
          acc[ti][tj] = __builtin_amdgcn_mfma_f32_16x16x32_f16(af[ti], bf[tj], acc[ti][tj], 0, 0, 0);
    }
  }

  // ---- epilogue state (init AFTER K-loop to shorten K-loop liveness) ----
  int srow = t & 63;   // i-side row within 64-row phase
  int sq = t >> 6;     // i-side column quarter (32 of 128 B-cols)
  int growA = bi * 128 + srow;
  int growB = growA + 64;
  int ct = t & 127;    // j-side col handled by this thread (B-row index in tile)
  int hh = t >> 7;     // j-side row-half within each phase (32 rows)
  int myA = idx[growA], myB = idx[growB], myC = idx[jbase + ct];

  float t5a[5], t5b[5], t5c[5];
  float mA = NEGINF, sA = 0.f, psA = 0.f, cnA = 0.f;
  float mB = NEGINF, sB = 0.f, psB = 0.f, cnB = 0.f;
  float mC = NEGINF, sC = 0.f, psC = 0.f, cnC = 0.f;
#pragma unroll
  for (int k = 0; k < 5; k++) { t5a[k] = NEGINF; t5b[k] = NEGINF; t5c[k] = NEGINF; }

  // ---- masks ----
  unsigned mMA = 0, mMB = 0;           // i-side: over 32 B-cols of quarter sq
  {
    const int4* ip = (const int4*)(idx + jbase + sq * 32);
#pragma unroll
    for (int q = 0; q < 8; q++) {
      int4 cv = ip[q];
      mMA |= ((unsigned)(cv.x == myA) << (q * 4)) | ((unsigned)(cv.y == myA) << (q * 4 + 1)) |
             ((unsigned)(cv.z == myA) << (q * 4 + 2)) | ((unsigned)(cv.w == myA) << (q * 4 + 3));
      mMB |= ((unsigned)(cv.x == myB) << (q * 4)) | ((unsigned)(cv.y == myB) << (q * 4 + 1)) |
             ((unsigned)(cv.z == myB) << (q * 4 + 2)) | ((unsigned)(cv.w == myB) << (q * 4 + 3));
    }
  }
  if (diag) {  // self-bit clear (self is a positive-mask hit but must be excluded)
    unsigned dA = (unsigned)(srow - sq * 32);
    if (dA < 32u) mMA &= ~(1u << dA);
    unsigned dB = (unsigned)(64 + srow - sq * 32);
    if (dB < 32u) mMB &= ~(1u << dB);
  }
  unsigned long long mC0 = 0, mC1 = 0;  // j-side: over 128 A-rows (phase0: 0..63, phase1: 64..127)
  if (!diag) {
    const int4* ip = (const int4*)(idx + bi * 128);
#pragma unroll
    for (int q = 0; q < 16; q++) {
      int4 cv = ip[q];
      unsigned long long bits = (unsigned long long)((unsigned)(cv.x == myC) |
          ((unsigned)(cv.y == myC) << 1) | ((unsigned)(cv.z == myC) << 2) |
          ((unsigned)(cv.w == myC) << 3));
      mC0 |= bits << (q * 4);
    }
#pragma unroll
    for (int q = 16; q < 32; q++) {
      int4 cv = ip[q];
      unsigned long long bits = (unsigned long long)((unsigned)(cv.x == myC) |
          ((unsigned)(cv.y == myC) << 1) | ((unsigned)(cv.z == myC) << 2) |
          ((unsigned)(cv.w == myC) << 3));
      mC1 |= bits << ((q - 16) * 4);
    }
  }

  // ---- epilogue: two phases; each phase scanned row-wise (i-side) and col-wise (j-side) ----
  // self element poisoned to -inf at dump time (diag tiles) -> scans need no self checks
  auto dump = [&]() {
#pragma unroll
    for (int ti = 0; ti < 4; ti++) {
      int r0 = ti * 16 + l4 * 4;
#pragma unroll
      for (int tj = 0; tj < 4; tj++) {
        int c = wc * 64 + tj * 16 + l15;
#pragma unroll
        for (int reg = 0; reg < 4; reg++) {
          float val = acc[ti][tj][reg];
          if (diag && c == wr * 64 + r0 + reg) val = NEGINF;  // wave-uniform guard
          Csm[(r0 + reg) * 129 + c] = val;
        }
      }
    }
  };
  auto scan_i = [&](float (&t5)[5], float& m, float& s, float& ps, float& cn,
                    unsigned match) {
    const float* rowp = Csm + srow * 129 + sq * 32;
#pragma unroll
    for (int it = 0; it < 8; it++) {
      float v0 = rowp[it * 4 + 0], v1 = rowp[it * 4 + 1];
      float v2 = rowp[it * 4 + 2], v3 = rowp[it * 4 + 3];
      ins5(t5, v0); ins5(t5, v1); ins5(t5, v2); ins5(t5, v3);
      unsigned m4 = (match >> (it * 4)) & 0xFu;
      if (m4) {
        float vv[4] = {v0, v1, v2, v3};
#pragma unroll
        for (int e = 0; e < 4; e++) {
          if ((m4 >> e) & 1u) {
            float v = vv[e];
            float nm = fmaxf(m, v);
            s = s * expf((m - nm) / TEMP) + expf((v - nm) / TEMP);
            m = nm;
            ps += v;
            cn += 1.f;
          }
        }
      }
    }
  };
  auto scan_j = [&](unsigned long long mfull) {
    const float* cp = Csm + ct;
    unsigned match = (unsigned)(mfull >> (hh * 32));
#pragma unroll
    for (int it = 0; it < 8; it++) {
      int r = hh * 32 + it * 4;
      float v0 = cp[(r + 0) * 129], v1 = cp[(r + 1) * 129];
      float v2 = cp[(r + 2) * 129], v3 = cp[(r + 3) * 129];
      ins5(t5c, v0); ins5(t5c, v1); ins5(t5c, v2); ins5(t5c, v3);
      unsigned m4 = (match >> (it * 4)) & 0xFu;
      if (m4) {
        float vv[4] = {v0, v1, v2, v3};
#pragma unroll
        for (int e = 0; e < 4; e++) {   // off-diag only: never self
          if ((m4 >> e) & 1u) {
            float v = vv[e];
            float nm = fmaxf(mC, v);
            sC = sC * expf((mC - nm) / TEMP) + expf((v - nm) / TEMP);
            mC = nm;
            psC += v;
            cnC += 1.f;
          }
        }
      }
    }
  };

  __syncthreads();               // all MFMA LDS reads done before C overwrite
  if (wr == 0) dump();           // A-rows 0..63
  __syncthreads();
  scan_i(t5a, mA, sA, psA, cnA, mMA);
  if (!diag) scan_j(mC0);
  __syncthreads();
  if (wr == 1) dump();           // A-rows 64..127
  __syncthreads();
  scan_i(t5b, mB, sB, psB, cnB, mMB);
  if (!diag) scan_j(mC1);

  // ---- in-block merge (LDS slots, stride 9: coprime 32 -> conflict-free) + store ----
  __syncthreads();
  {
    float* slotA = Csm + (size_t)(sq * 128 + srow) * 9;        // i-side: 512 slots
    float* slotB = Csm + (size_t)(sq * 128 + 64 + srow) * 9;
#pragma unroll
    for (int k = 0; k < 5; k++) { slotA[k] = t5a[k]; slotB[k] = t5b[k]; }
    slotA[5] = mA; slotA[6] = sA; slotA[7] = psA; slotA[8] = cnA;
    slotB[5] = mB; slotB[6] = sB; slotB[7] = psB; slotB[8] = cnB;
    if (!diag) {
      float* sc = Csm + 4608 + (size_t)(hh * 128 + ct) * 9;    // j-side: 256 slots
#pragma unroll
      for (int k = 0; k < 5; k++) sc[k] = t5c[k];
      sc[5] = mC; sc[6] = sC; sc[7] = psC; sc[8] = cnC;
    }
  }
  __syncthreads();
  if (t < 128) {                 // i-side: merge 4 quarters for A-row t -> slot bj
    float t5[5];
    float m = NEGINF, s = 0.f, ps = 0.f, cn = 0.f;
#pragma unroll
    for (int k = 0; k < 5; k++) t5[k] = NEGINF;
#pragma unroll
    for (int q = 0; q < 4; q++) {
      const float* s9 = Csm + (size_t)(q * 128 + t) * 9;
      for (int k = 0; k < 5; k++) {
        float v = s9[k];
        if (!(v > t5[4])) break;
        ins5(t5, v);
      }
      lse_merge(m, s, s9[5], s9[6]);
      ps += s9[7];
      cn += s9[8];
    }
    store_rec(toppart + ((size_t)(bi * 128 + t) * 64 + bj) * 12, t5, m, s, ps, cn);
  } else if (!diag) {            // j-side: merge 2 halves for B-row (t-128) -> slot bi
    int c = t - 128;
    float t5[5];
    float m = NEGINF, s = 0.f, ps = 0.f, cn = 0.f;
#pragma unroll
    for (int k = 0; k < 5; k++) t5[k] = NEGINF;
#pragma unroll
    for (int h = 0; h < 2; h++) {
      const float* s9 = Csm + 4608 + (size_t)(h * 128 + c) * 9;
      for (int k = 0; k < 5; k++) {
        float v = s9[k];
        if (!(v > t5[4])) break;
        ins5(t5, v);
      }
      lse_merge(m, s, s9[5], s9[6]);
      ps += s9[7];
      cn += s9[8];
    }
    store_rec(toppart + ((size_t)(jbase + c) * 64 + bi) * 12, t5, m, s, ps, cn);
  }
}

// ---------- fallback GEMM (R3 structure, 12 parts) for small workspaces ----------
// record layout: toppart[(row*NPART + part)*12]
__global__ __launch_bounds__(256, 3) void k_gemm_fb(const _Float16* __restrict__ f16,
                                                    const int* __restrict__ idx,
                                                    float* __restrict__ toppart) {
  __shared__ float Csm[64 * 129];
  _Float16* Asm = (_Float16*)Csm;
  _Float16* Bsm = Asm + 128 * 64;
  int t = threadIdx.x;
  int w = t >> 6, lane = t & 63;
  int wr = w >> 1, wc = w & 1;
  int l15 = lane & 15, l4 = lane >> 4;
  int b = blockIdx.x;
  int part = b % NPART;
  int bi = b / NPART;
  int startp = part < 4 ? part * 6 : 24 + (part - 4) * 5;
  int cntp = part < 4 ? 6 : 5;
  int srow = t & 63, sq = t >> 6;
  int growA = bi * 128 + srow, growB = growA + 64;
  int myA = idx[growA], myB = idx[growB];
  float t5a[5], t5b[5];
  float mA = NEGINF, sA = 0.f, psA = 0.f, cnA = 0.f;
  float mB = NEGINF, sB = 0.f, psB = 0.f, cnB = 0.f;
#pragma unroll
  for (int k = 0; k < 5; k++) { t5a[k] = NEGINF; t5b[k] = NEGINF; }
  int swz = l15 & 7;
  for (int jj = 0; jj < cntp; jj++) {
    int jbase = (startp + jj) * 128;
    f32x4 acc[4][4] = {};
    for (int kc = 0; kc < 8; kc++) {
      int k0 = kc * 64;
      __syncthreads();
#pragma unroll
      for (int p = 0; p < 4; p++) {
        int u = p * 256 + t;
        int row = u >> 3;
        int cko = (u & 7) ^ (row & 7);
        GLOAD16(f16 + (size_t)(bi * 128 + row) * DIM + k0 + cko * 8, Asm + u * 8);
        GLOAD16(f16 + (size_t)(jbase + row) * DIM + k0 + cko * 8, Bsm + u * 8);
      }
      __syncthreads();
#pragma unroll
      for (int s = 0; s < 2; s++) {
        half8 af[4], bf[4];
#pragma unroll
        for (int ti = 0; ti < 4; ti++) {
          int row = wr * 64 + ti * 16 + l15;
          af[ti] = *(const half8*)(Asm + (row * 8 + ((s * 4 + l4) ^ swz)) * 8);
        }
#pragma unroll
        for (int tj = 0; tj < 4; tj++) {
          int row = wc * 64 + tj * 16 + l15;
          bf[tj] = *(const half8*)(Bsm + (row * 8 + ((s * 4 + l4) ^ swz)) * 8);
        }
#pragma unroll
        for (int ti = 0; ti < 4; ti++)
#pragma unroll
          for (int tj = 0; tj < 4; tj++)
            acc[ti][tj] = __builtin_amdgcn_mfma_f32_16x16x32_f16(af[ti], bf[tj], acc[ti][tj], 0, 0, 0);
      }
    }
    unsigned mMA = 0, mMB = 0;
    {
      const int4* ip = (const int4*)(idx + jbase + sq * 32);
#pragma unroll
      for (int q = 0; q < 8; q++) {
        int4 cv = ip[q];
        mMA |= ((unsigned)(cv.x == myA) << (q * 4)) | ((unsigned)(cv.y == myA) << (q * 4 + 1)) |
               ((unsigned)(cv.z == myA) << (q * 4 + 2)) | ((unsigned)(cv.w == myA) << (q * 4 + 3));
        mMB |= ((unsigned)(cv.x == myB) << (q * 4)) | ((unsigned)(cv.y == myB) << (q * 4 + 1)) |
               ((unsigned)(cv.z == myB) << (q * 4 + 2)) | ((unsigned)(cv.w == myB) << (q * 4 + 3));
      }
    }
    auto dump = [&]() {
#pragma unroll
      for (int ti = 0; ti < 4; ti++) {
        int r0 = ti * 16 + l4 * 4;
#pragma unroll
        for (int tj = 0; tj < 4; tj++) {
          int c = wc * 64 + tj * 16 + l15;
#pragma unroll
          for (int reg = 0; reg < 4; reg++)
            Csm[(r0 + reg) * 129 + c] = acc[ti][tj][reg];
        }
      }
    };
    auto scan = [&](float (&t5)[5], float& m, float& s, float& ps, float& cn,
                    int grow, unsigned match) {
      const float* rowp = Csm + srow * 129 + sq * 32;
      int gc0 = jbase + sq * 32;
#pragma unroll
      for (int it = 0; it < 8; it++) {
        float v0 = rowp[it * 4 + 0], v1 = rowp[it * 4 + 1];
        float v2 = rowp[it * 4 + 2], v3 = rowp[it * 4 + 3];
        unsigned m4 = (match >> (it * 4)) & 0xFu;
        float mx = fmaxf(fmaxf(v0, v1), fmaxf(v2, v3));
        if (mx > t5[4] || m4) {
          int gc = gc0 + it * 4;
          float vv[4] = {v0, v1, v2, v3};
#pragma unroll
          for (int e = 0; e < 4; e++) {
            bool notself = (gc + e != grow);
            if (((m4 >> e) & 1u) && notself) {
              float v = vv[e];
              float nm = fmaxf(m, v);
              s = s * expf((m - nm) / TEMP) + expf((v - nm) / TEMP);
              m = nm;
              ps += v;
              cn += 1.f;
            }
            if (vv[e] > t5[4] && notself) ins5(t5, vv[e]);
          }
        }
      }
    };
    __syncthreads();
    if (wr == 0) dump();
    __syncthreads();
    scan(t5a, mA, sA, psA, cnA, growA, mMA);
    __syncthreads();
    if (wr == 1) dump();
    __syncthreads();
    scan(t5b, mB, sB, psB, cnB, growB, mMB);
  }
  __syncthreads();
  {
    float* slotA = Csm + (size_t)(sq * 128 + srow) * 9;
    float* slotB = Csm + (size_t)(sq * 128 + 64 + srow) * 9;
#pragma unroll
    for (int k = 0; k < 5; k++) { slotA[k] = t5a[k]; slotB[k] = t5b[k]; }
    slotA[5] = mA; slotA[6] = sA; slotA[7] = psA; slotA[8] = cnA;
    slotB[5] = mB; slotB[6] = sB; slotB[7] = psB; slotB[8] = cnB;
  }
  __syncthreads();
  if (t < 128) {
    float t5[5];
    float m = NEGINF, s = 0.f, ps = 0.f, cn = 0.f;
#pragma unroll
    for (int k = 0; k < 5; k++) t5[k] = NEGINF;
#pragma unroll
    for (int q = 0; q < 4; q++) {
      const float* s9 = Csm + (size_t)(q * 128 + t) * 9;
      for (int k = 0; k < 5; k++) {
        float v = s9[k];
        if (!(v > t5[4])) break;
        ins5(t5, v);
      }
      lse_merge(m, s, s9[5], s9[6]);
      ps += s9[7];
      cn += s9[8];
    }
    store_rec(toppart + ((size_t)(bi * 128 + t) * NPART + part) * 12, t5, m, s, ps, cn);
  }
}

// ---------- wave-parallel merge: one wave per row, lane p owns slot p ----------
__global__ __launch_bounds__(256) void k_merge(const float* __restrict__ toppart,
                                               float* __restrict__ merged,
                                               float* __restrict__ bmax, int nslots) {
  __shared__ float red[4];
  int t = threadIdx.x;
  int lane = t & 63, w = t >> 6;
  int row = blockIdx.x * 4 + w;

  float t5[5], m, s, ps, cn;
  if (lane < nslots) {
    const float* r12 = toppart + ((size_t)row * nslots + lane) * 12;
    float4 a = *(const float4*)r12;
    float4 bq = *(const float4*)(r12 + 4);
    float4 cq = *(const float4*)(r12 + 8);
    t5[0] = a.x; t5[1] = a.y; t5[2] = a.z; t5[3] = a.w; t5[4] = bq.x;
    m = bq.y; s = bq.z; ps = bq.w; cn = cq.x;
  } else {
    t5[0] = t5[1] = t5[2] = t5[3] = t5[4] = NEGINF;
    m = NEGINF; s = 0.f; ps = 0.f; cn = 0.f;
  }
#pragma unroll
  for (int off = 32; off > 0; off >>= 1) {
    float tp[5];
#pragma unroll
    for (int k = 0; k < 5; k++) tp[k] = __shfl_xor(t5[k], off, 64);
    float mp = __shfl_xor(m, off, 64), sp = __shfl_xor(s, off, 64);
    float pp = __shfl_xor(ps, off, 64), cp = __shfl_xor(cn, off, 64);
#pragma unroll
    for (int k = 0; k < 5; k++)
      if (tp[k] > t5[4]) ins5(t5, tp[k]);
    lse_merge(m, s, mp, sp);
    ps += pp;
    cn += cp;
  }
  if (lane == 0) {
    float* d = merged + (size_t)row * 8;
    *(float4*)d = make_float4(t5[0], t5[1], t5[2], t5[3]);
    *(float4*)(d + 4) = make_float4(t5[4], s, ps, cn);   // m not needed downstream
    red[w] = t5[0];
  }
  __syncthreads();
  if (t == 0) bmax[blockIdx.x] = fmaxf(fmaxf(red[0], red[1]), fmaxf(red[2], red[3]));
}

// ---------- per-row loss; Mg from bmax; atomic partial sums; last block writes mean ----------
__global__ __launch_bounds__(256) void k_final(const float* __restrict__ merged,
                                               const float* __restrict__ bmax, int nb,
                                               unsigned* __restrict__ cells,
                                               float* __restrict__ out) {
  __shared__ float red[256];
  int t = threadIdx.x;
  float mg = NEGINF;
  for (int i = t; i < nb; i += 256) mg = fmaxf(mg, bmax[i]);
  red[t] = mg;
  __syncthreads();
  for (int o = 128; o > 0; o >>= 1) {
    if (t < o) red[t] = fmaxf(red[t], red[t + o]);
    __syncthreads();
  }
  float Mg = red[0];
  __syncthreads();

  int row = blockIdx.x * 256 + t;
  const float* m8 = merged + (size_t)row * 8;
  float4 a = *(const float4*)m8;
  float4 bq = *(const float4*)(m8 + 4);
  float h = expf((a.x - Mg) / TEMP) + expf((a.y - Mg) / TEMP) + expf((a.z - Mg) / TEMP) +
            expf((a.w - Mg) / TEMP) + expf((bq.x - Mg) / TEMP);
  float s = bq.y, ps = bq.z, cn = bq.w;
  float v = 0.f;
  if (cn > 0.f) v = logf(s + h) - (ps / cn) / TEMP;
  red[t] = v;
  __syncthreads();
  for (int o = 128; o > 0; o >>= 1) {
    if (t < o) red[t] += red[t + o];
    __syncthreads();
  }
  if (t == 0) {
    atomicAdd((float*)cells + 1, red[0]);
    __threadfence();
    unsigned done = atomicAdd(&cells[2], 1u);
    if (done == gridDim.x - 1) {
      float total = atomicAdd((float*)cells + 1, 0.0f);  // coherent read
      out[0] = total * (1.0f / (float)BN);
    }
  }
}

extern "C" void kernel_launch(void* const* d_in, const int* in_sizes, int n_in,
                              void* d_out, int out_size, void* d_ws, size_t ws_size,
                              hipStream_t stream) {
  const float* feat = (const float*)d_in[0];
  const int* idx = (const int*)d_in[1];
  float* out = (float*)d_out;
  char* ws = (char*)d_ws;

  _Float16* f16 = (_Float16*)ws;                 // 8 MB (row-major normalized fp16)
  const size_t F16B = (size_t)8 * 1024 * 1024;

  // triangle path: 8 MB + toppart 24 MB + merged 256 KB + bmax 8 KB + cells
  const size_t TRI_TOP = F16B;
  const size_t TRI_MERGED = TRI_TOP + (size_t)BN * 64 * 12 * 4;
  const size_t TRI_BMAX = TRI_MERGED + (size_t)BN * 8 * 4;
  const size_t TRI_CELLS = TRI_BMAX + (size_t)(BN / 4) * 4;
  const size_t TRI_NEED = TRI_CELLS + 64;

  if (ws_size >= TRI_NEED) {
    float* toppart = (float*)(ws + TRI_TOP);
    float* merged = (float*)(ws + TRI_MERGED);
    float* bmax = (float*)(ws + TRI_BMAX);
    unsigned* cells = (unsigned*)(ws + TRI_CELLS);
    k_normalize<<<dim3(BN / 4), dim3(256), 0, stream>>>(feat, f16, cells);
    k_tri<<<dim3(2080), dim3(256), 0, stream>>>(f16, idx, toppart);
    k_merge<<<dim3(BN / 4), dim3(256), 0, stream>>>(toppart, merged, bmax, 64);
    k_final<<<dim3(BN / 256), dim3(256), 0, stream>>>(merged, bmax, BN / 4, cells, out);
  } else {
    // fallback: 8 MB + toppart 4.5 MB + merged + bmax + cells (< 13.1 MB)
    const size_t FB_TOP = F16B;
    const size_t FB_MERGED = FB_TOP + (size_t)BN * NPART * 12 * 4;
    const size_t FB_BMAX = FB_MERGED + (size_t)BN * 8 * 4;
    const size_t FB_CELLS = FB_BMAX + (size_t)(BN / 4) * 4;
    float* toppart = (float*)(ws + FB_TOP);
    float* merged = (float*)(ws + FB_MERGED);
    float* bmax = (float*)(ws + FB_BMAX);
    unsigned* cells = (unsigned*)(ws + FB_CELLS);
    k_normalize<<<dim3(BN / 4), dim3(256), 0, stream>>>(feat, f16, cells);
    k_gemm_fb<<<dim3((BN / 128) * NPART), dim3(256), 0, stream>>>(f16, idx, toppart);
    k_merge<<<dim3(BN / 4), dim3(256), 0, stream>>>(toppart, merged, bmax, NPART);
    k_final<<<dim3(BN / 256), dim3(256), 0, stream>>>(merged, bmax, BN / 4, cells, out);
  }
}

// Round 11
// 158.452 us; speedup vs baseline: 1.2023x; 1.2023x over previous
//
#include <hip/hip_runtime.h>

#define BN 8192
#define DIM 512
#define TEMP 0.07f
#define INVT (1.0f / TEMP)
#define NPART 12
#define NEGINF (-__builtin_inff())

typedef _Float16 half8 __attribute__((ext_vector_type(8)));
typedef float f32x4 __attribute__((ext_vector_type(4)));

// async 16B global->LDS (wave-uniform base + lane*16 on the LDS side)
#define GLOAD16(gp, lp) __builtin_amdgcn_global_load_lds( \
    (__attribute__((address_space(1))) const void*)(gp),  \
    (__attribute__((address_space(3))) void*)(lp), 16, 0, 0)

// branch-free sorted-desc top-5 insert: 5 x (max+min) = 10 VALU, no compares
__device__ __forceinline__ void ins5(float t5[5], float v) {
#pragma unroll
  for (int k = 0; k < 5; k++) {
    float hi = fmaxf(t5[k], v);
    v = fminf(t5[k], v);
    t5[k] = hi;
  }
}

// ---------- 1. L2-normalize fp32 rows -> fp16 matrix (one wave per row, row-major) ----------
__global__ __launch_bounds__(256) void k_normalize(const float* __restrict__ feat,
                                                   _Float16* __restrict__ f16,
                                                   unsigned* __restrict__ cells) {
  if (blockIdx.x == 0 && threadIdx.x == 0) {
    ((float*)cells)[1] = 0.0f;      // loss-sum accumulator
    cells[2] = 0u;                  // completion counter for k_final
  }
  int gid = blockIdx.x * 256 + threadIdx.x;
  int row = gid >> 6, lane = gid & 63;
  const float4* rp = (const float4*)(feat + (size_t)row * DIM);
  float4 v0 = rp[lane * 2];
  float4 v1 = rp[lane * 2 + 1];
  float ss = v0.x * v0.x + v0.y * v0.y + v0.z * v0.z + v0.w * v0.w +
             v1.x * v1.x + v1.y * v1.y + v1.z * v1.z + v1.w * v1.w;
#pragma unroll
  for (int m = 1; m < 64; m <<= 1) ss += __shfl_xor(ss, m, 64);
  float r = 1.0f / fmaxf(sqrtf(ss), 1e-12f);
  half8 o;
  o[0] = (_Float16)(v0.x * r); o[1] = (_Float16)(v0.y * r);
  o[2] = (_Float16)(v0.z * r); o[3] = (_Float16)(v0.w * r);
  o[4] = (_Float16)(v1.x * r); o[5] = (_Float16)(v1.y * r);
  o[6] = (_Float16)(v1.z * r); o[7] = (_Float16)(v1.w * r);
  ((half8*)(f16 + (size_t)row * DIM))[lane] = o;
}

// record: t5[5], m(max pos sim), S(sum exp(v/T) over pos), ps, cn  (12 floats, 48 B)
// NOTE: direct-sum form — max sim = 1 so exp(v/T) <= e^14.3 ~ 1.6e6, no overflow;
// the reference's row_max-subtracted sum is reconstructed as S*exp(-m/T) in k_final.
__device__ __forceinline__ void store_rec(float* d, const float t5[5], float m, float S,
                                          float ps, float cn) {
  *(float4*)d = make_float4(t5[0], t5[1], t5[2], t5[3]);
  *(float4*)(d + 4) = make_float4(t5[4], m, S, ps);
  *(float4*)(d + 8) = make_float4(cn, 0.f, 0.f, 0.f);
}

// ======================================================================
// Triangle GEMM: jobs = (bi,bj), bi<=bj. Off-diag jobs harvest BOTH sides
// of the symmetric sim tile. Record layout: toppart[(row*64 + slot)*12].
// launch_bounds(256,3): proven no-spill config (both (256,4) attempts spilled
// the ~76-reg epilogue state -> 130-151 MB WRITE and net loss; R8/R10).
// ======================================================================
__global__ __launch_bounds__(256, 3) void k_tri(const _Float16* __restrict__ f16,
                                                const int* __restrict__ idx,
                                                float* __restrict__ toppart) {
  __shared__ float Csm[64 * 129];          // 33,024 B; C half-tile (64 A-rows x 128 B-cols)
  _Float16* Asm = (_Float16*)Csm;          // staging alias: 128 rows x 8 granules x 8 halfs = 16 KB
  _Float16* Bsm = Asm + 128 * 64;          // next 16 KB

  int t = threadIdx.x;
  int w = t >> 6, lane = t & 63;
  int wr = w >> 1, wc = w & 1;
  int l15 = lane & 15, l4 = lane >> 4;

  // decode (bi,bj) from blockIdx: off(g) = g*64 - g*(g-1)/2
  int b = blockIdx.x;
  int bi = (int)(64.5f - sqrtf(64.5f * 64.5f - 2.0f * (float)b));
  bi = bi < 0 ? 0 : (bi > 63 ? 63 : bi);
  while (bi > 0 && (bi * 64 - (bi * (bi - 1)) / 2) > b) bi--;
  while (((bi + 1) * 64 - ((bi + 1) * bi) / 2) <= b) bi++;
  int bj = bi + (b - (bi * 64 - (bi * (bi - 1)) / 2));
  bool diag = (bi == bj);

  int swz = l15 & 7;   // fragment-read XOR swizzle (matches staging granule permutation)
  int jbase = bj * 128;
  f32x4 acc[4][4] = {};

  // hoist staging addresses out of the K-loop (row/cko invariant across kc)
  const _Float16* gA[4];
  const _Float16* gB[4];
  int ldsu[4];
#pragma unroll
  for (int p = 0; p < 4; p++) {
    int u = p * 256 + t;
    int row = u >> 3;
    int cko = (u & 7) ^ (row & 7);
    gA[p] = f16 + (size_t)(bi * 128 + row) * DIM + cko * 8;
    gB[p] = f16 + (size_t)(jbase + row) * DIM + cko * 8;
    ldsu[p] = u * 8;
  }

  // ---- K-loop (R3 structure, proven) ----
  for (int kc = 0; kc < 8; kc++) {
    int k0 = kc * 64;
    __syncthreads();
#pragma unroll
    for (int p = 0; p < 4; p++) {
      GLOAD16(gA[p] + k0, Asm + ldsu[p]);
      GLOAD16(gB[p] + k0, Bsm + ldsu[p]);
    }
    __syncthreads();
#pragma unroll
    for (int s = 0; s < 2; s++) {
      half8 af[4], bf[4];
#pragma unroll
      for (int ti = 0; ti < 4; ti++) {
        int row = wr * 64 + ti * 16 + l15;
        af[ti] = *(const half8*)(Asm + (row * 8 + ((s * 4 + l4) ^ swz)) * 8);
      }
#pragma unroll
      for (int tj = 0; tj < 4; tj++) {
        int row = wc * 64 + tj * 16 + l15;
        bf[tj] = *(const half8*)(Bsm + (row * 8 + ((s * 4 + l4) ^ swz)) * 8);
      }
#pragma unroll
      for (int ti = 0; ti < 4; ti++)
#pragma unroll
        for (int tj = 0; tj < 4; tj++)
          acc[ti][tj] = __builtin_amdgcn_mfma_f32_16x16x32_f16(af[ti], bf[tj], acc[ti][tj], 0, 0, 0);
    }
  }

  // ---- epilogue state (init AFTER K-loop to shorten K-loop liveness) ----
  int srow = t & 63;   // i-side row within 64-row phase
  int sq = t >> 6;     // i-side column quarter (32 of 128 B-cols)
  int growA = bi * 128 + srow;
  int growB = growA + 64;
  int ct = t & 127;    // j-side col handled by this thread (B-row index in tile)
  int hh = t >> 7;     // j-side row-half within each phase (32 rows)
  int myA = idx[growA], myB = idx[growB], myC = idx[jbase + ct];

  float t5a[5], t5b[5], t5c[5];
  float mA = NEGINF, SA = 0.f, psA = 0.f, cnA = 0.f;
  float mB = NEGINF, SB = 0.f, psB = 0.f, cnB = 0.f;
  float mC = NEGINF, SC = 0.f, psC = 0.f, cnC = 0.f;
#pragma unroll
  for (int k = 0; k < 5; k++) { t5a[k] = NEGINF; t5b[k] = NEGINF; t5c[k] = NEGINF; }

  // ---- masks ----
  unsigned mMA = 0, mMB = 0;           // i-side: over 32 B-cols of quarter sq
  {
    const int4* ip = (const int4*)(idx + jbase + sq * 32);
#pragma unroll
    for (int q = 0; q < 8; q++) {
      int4 cv = ip[q];
      mMA |= ((unsigned)(cv.x == myA) << (q * 4)) | ((unsigned)(cv.y == myA) << (q * 4 + 1)) |
             ((unsigned)(cv.z == myA) << (q * 4 + 2)) | ((unsigned)(cv.w == myA) << (q * 4 + 3));
      mMB |= ((unsigned)(cv.x == myB) << (q * 4)) | ((unsigned)(cv.y == myB) << (q * 4 + 1)) |
             ((unsigned)(cv.z == myB) << (q * 4 + 2)) | ((unsigned)(cv.w == myB) << (q * 4 + 3));
    }
  }
  if (diag) {  // self-bit clear (self is a positive-mask hit but must be excluded)
    unsigned dA = (unsigned)(srow - sq * 32);
    if (dA < 32u) mMA &= ~(1u << dA);
    unsigned dB = (unsigned)(64 + srow - sq * 32);
    if (dB < 32u) mMB &= ~(1u << dB);
  }
  unsigned long long mC0 = 0, mC1 = 0;  // j-side: over 128 A-rows (phase0: 0..63, phase1: 64..127)
  if (!diag) {
    const int4* ip = (const int4*)(idx + bi * 128);
#pragma unroll
    for (int q = 0; q < 16; q++) {
      int4 cv = ip[q];
      unsigned long long bits = (unsigned long long)((unsigned)(cv.x == myC) |
          ((unsigned)(cv.y == myC) << 1) | ((unsigned)(cv.z == myC) << 2) |
          ((unsigned)(cv.w == myC) << 3));
      mC0 |= bits << (q * 4);
    }
#pragma unroll
    for (int q = 16; q < 32; q++) {
      int4 cv = ip[q];
      unsigned long long bits = (unsigned long long)((unsigned)(cv.x == myC) |
          ((unsigned)(cv.y == myC) << 1) | ((unsigned)(cv.z == myC) << 2) |
          ((unsigned)(cv.w == myC) << 3));
      mC1 |= bits << ((q - 16) * 4);
    }
  }

  // ---- epilogue: two phases; each phase scanned row-wise (i-side) and col-wise (j-side) ----
  // self element poisoned to -inf at dump time (diag tiles) -> scans need no self checks
  auto dump = [&]() {
#pragma unroll
    for (int ti = 0; ti < 4; ti++) {
      int r0 = ti * 16 + l4 * 4;
#pragma unroll
      for (int tj = 0; tj < 4; tj++) {
        int c = wc * 64 + tj * 16 + l15;
#pragma unroll
        for (int reg = 0; reg < 4; reg++) {
          float val = acc[ti][tj][reg];
          if (diag && c == wr * 64 + r0 + reg) val = NEGINF;  // wave-uniform guard
          Csm[(r0 + reg) * 129 + c] = val;
        }
      }
    }
  };
  auto scan_i = [&](float (&t5)[5], float& m, float& S, float& ps, float& cn,
                    unsigned match) {
    const float* rowp = Csm + srow * 129 + sq * 32;
#pragma unroll
    for (int it = 0; it < 8; it++) {
      float v0 = rowp[it * 4 + 0], v1 = rowp[it * 4 + 1];
      float v2 = rowp[it * 4 + 2], v3 = rowp[it * 4 + 3];
      ins5(t5, v0); ins5(t5, v1); ins5(t5, v2); ins5(t5, v3);
      unsigned m4 = (match >> (it * 4)) & 0xFu;
      if (m4) {
        float vv[4] = {v0, v1, v2, v3};
#pragma unroll
        for (int e = 0; e < 4; e++) {
          if ((m4 >> e) & 1u) {   // positive pair: direct-exp sum (no online LSE chain)
            float v = vv[e];
            S += __expf(v * INVT);
            m = fmaxf(m, v);
            ps += v;
            cn += 1.f;
          }
        }
      }
    }
  };
  auto scan_j = [&](unsigned long long mfull) {
    const float* cp = Csm + ct;
    unsigned match = (unsigned)(mfull >> (hh * 32));
#pragma unroll
    for (int it = 0; it < 8; it++) {
      int r = hh * 32 + it * 4;
      float v0 = cp[(r + 0) * 129], v1 = cp[(r + 1) * 129];
      float v2 = cp[(r + 2) * 129], v3 = cp[(r + 3) * 129];
      ins5(t5c, v0); ins5(t5c, v1); ins5(t5c, v2); ins5(t5c, v3);
      unsigned m4 = (match >> (it * 4)) & 0xFu;
      if (m4) {
        float vv[4] = {v0, v1, v2, v3};
#pragma unroll
        for (int e = 0; e < 4; e++) {   // off-diag only: never self
          if ((m4 >> e) & 1u) {
            float v = vv[e];
            SC += __expf(v * INVT);
            mC = fmaxf(mC, v);
            psC += v;
            cnC += 1.f;
          }
        }
      }
    }
  };

  __syncthreads();               // all MFMA LDS reads done before C overwrite
  if (wr == 0) dump();           // A-rows 0..63
  __syncthreads();
  scan_i(t5a, mA, SA, psA, cnA, mMA);
  if (!diag) scan_j(mC0);
  __syncthreads();
  if (wr == 1) dump();           // A-rows 64..127
  __syncthreads();
  scan_i(t5b, mB, SB, psB, cnB, mMB);
  if (!diag) scan_j(mC1);

  // ---- in-block merge (LDS slots, stride 9: coprime 32 -> conflict-free) + store ----
  __syncthreads();
  {
    float* slotA = Csm + (size_t)(sq * 128 + srow) * 9;        // i-side: 512 slots
    float* slotB = Csm + (size_t)(sq * 128 + 64 + srow) * 9;
#pragma unroll
    for (int k = 0; k < 5; k++) { slotA[k] = t5a[k]; slotB[k] = t5b[k]; }
    slotA[5] = mA; slotA[6] = SA; slotA[7] = psA; slotA[8] = cnA;
    slotB[5] = mB; slotB[6] = SB; slotB[7] = psB; slotB[8] = cnB;
    if (!diag) {
      float* sc = Csm + 4608 + (size_t)(hh * 128 + ct) * 9;    // j-side: 256 slots
#pragma unroll
      for (int k = 0; k < 5; k++) sc[k] = t5c[k];
      sc[5] = mC; sc[6] = SC; sc[7] = psC; sc[8] = cnC;
    }
  }
  __syncthreads();
  if (t < 128) {                 // i-side: merge 4 quarters for A-row t -> slot bj
    float t5[5];
    float m = NEGINF, S = 0.f, ps = 0.f, cn = 0.f;
#pragma unroll
    for (int k = 0; k < 5; k++) t5[k] = NEGINF;
#pragma unroll
    for (int q = 0; q < 4; q++) {
      const float* s9 = Csm + (size_t)(q * 128 + t) * 9;
      for (int k = 0; k < 5; k++) {
        float v = s9[k];
        if (!(v > t5[4])) break;
        ins5(t5, v);
      }
      m = fmaxf(m, s9[5]);
      S += s9[6];
      ps += s9[7];
      cn += s9[8];
    }
    store_rec(toppart + ((size_t)(bi * 128 + t) * 64 + bj) * 12, t5, m, S, ps, cn);
  } else if (!diag) {            // j-side: merge 2 halves for B-row (t-128) -> slot bi
    int c = t - 128;
    float t5[5];
    float m = NEGINF, S = 0.f, ps = 0.f, cn = 0.f;
#pragma unroll
    for (int k = 0; k < 5; k++) t5[k] = NEGINF;
#pragma unroll
    for (int h = 0; h < 2; h++) {
      const float* s9 = Csm + 4608 + (size_t)(h * 128 + c) * 9;
      for (int k = 0; k < 5; k++) {
        float v = s9[k];
        if (!(v > t5[4])) break;
        ins5(t5, v);
      }
      m = fmaxf(m, s9[5]);
      S += s9[6];
      ps += s9[7];
      cn += s9[8];
    }
    store_rec(toppart + ((size_t)(jbase + c) * 64 + bi) * 12, t5, m, S, ps, cn);
  }
}

// ---------- fallback GEMM (R3 structure, 12 parts) for small workspaces ----------
// record layout: toppart[(row*NPART + part)*12]
__global__ __launch_bounds__(256, 3) void k_gemm_fb(const _Float16* __restrict__ f16,
                                                    const int* __restrict__ idx,
                                                    float* __restrict__ toppart) {
  __shared__ float Csm[64 * 129];
  _Float16* Asm = (_Float16*)Csm;
  _Float16* Bsm = Asm + 128 * 64;
  int t = threadIdx.x;
  int w = t >> 6, lane = t & 63;
  int wr = w >> 1, wc = w & 1;
  int l15 = lane & 15, l4 = lane >> 4;
  int b = blockIdx.x;
  int part = b % NPART;
  int bi = b / NPART;
  int startp = part < 4 ? part * 6 : 24 + (part - 4) * 5;
  int cntp = part < 4 ? 6 : 5;
  int srow = t & 63, sq = t >> 6;
  int growA = bi * 128 + srow, growB = growA + 64;
  int myA = idx[growA], myB = idx[growB];
  float t5a[5], t5b[5];
  float mA = NEGINF, SA = 0.f, psA = 0.f, cnA = 0.f;
  float mB = NEGINF, SB = 0.f, psB = 0.f, cnB = 0.f;
#pragma unroll
  for (int k = 0; k < 5; k++) { t5a[k] = NEGINF; t5b[k] = NEGINF; }
  int swz = l15 & 7;
  for (int jj = 0; jj < cntp; jj++) {
    int jbase = (startp + jj) * 128;
    f32x4 acc[4][4] = {};
    for (int kc = 0; kc < 8; kc++) {
      int k0 = kc * 64;
      __syncthreads();
#pragma unroll
      for (int p = 0; p < 4; p++) {
        int u = p * 256 + t;
        int row = u >> 3;
        int cko = (u & 7) ^ (row & 7);
        GLOAD16(f16 + (size_t)(bi * 128 + row) * DIM + k0 + cko * 8, Asm + u * 8);
        GLOAD16(f16 + (size_t)(jbase + row) * DIM + k0 + cko * 8, Bsm + u * 8);
      }
      __syncthreads();
#pragma unroll
      for (int s = 0; s < 2; s++) {
        half8 af[4], bf[4];
#pragma unroll
        for (int ti = 0; ti < 4; ti++) {
          int row = wr * 64 + ti * 16 + l15;
          af[ti] = *(const half8*)(Asm + (row * 8 + ((s * 4 + l4) ^ swz)) * 8);
        }
#pragma unroll
        for (int tj = 0; tj < 4; tj++) {
          int row = wc * 64 + tj * 16 + l15;
          bf[tj] = *(const half8*)(Bsm + (row * 8 + ((s * 4 + l4) ^ swz)) * 8);
        }
#pragma unroll
        for (int ti = 0; ti < 4; ti++)
#pragma unroll
          for (int tj = 0; tj < 4; tj++)
            acc[ti][tj] = __builtin_amdgcn_mfma_f32_16x16x32_f16(af[ti], bf[tj], acc[ti][tj], 0, 0, 0);
      }
    }
    unsigned mMA = 0, mMB = 0;
    {
      const int4* ip = (const int4*)(idx + jbase + sq * 32);
#pragma unroll
      for (int q = 0; q < 8; q++) {
        int4 cv = ip[q];
        mMA |= ((unsigned)(cv.x == myA) << (q * 4)) | ((unsigned)(cv.y == myA) << (q * 4 + 1)) |
               ((unsigned)(cv.z == myA) << (q * 4 + 2)) | ((unsigned)(cv.w == myA) << (q * 4 + 3));
        mMB |= ((unsigned)(cv.x == myB) << (q * 4)) | ((unsigned)(cv.y == myB) << (q * 4 + 1)) |
               ((unsigned)(cv.z == myB) << (q * 4 + 2)) | ((unsigned)(cv.w == myB) << (q * 4 + 3));
      }
    }
    auto dump = [&]() {
#pragma unroll
      for (int ti = 0; ti < 4; ti++) {
        int r0 = ti * 16 + l4 * 4;
#pragma unroll
        for (int tj = 0; tj < 4; tj++) {
          int c = wc * 64 + tj * 16 + l15;
#pragma unroll
          for (int reg = 0; reg < 4; reg++)
            Csm[(r0 + reg) * 129 + c] = acc[ti][tj][reg];
        }
      }
    };
    auto scan = [&](float (&t5)[5], float& m, float& S, float& ps, float& cn,
                    int grow, unsigned match) {
      const float* rowp = Csm + srow * 129 + sq * 32;
      int gc0 = jbase + sq * 32;
#pragma unroll
      for (int it = 0; it < 8; it++) {
        float v0 = rowp[it * 4 + 0], v1 = rowp[it * 4 + 1];
        float v2 = rowp[it * 4 + 2], v3 = rowp[it * 4 + 3];
        unsigned m4 = (match >> (it * 4)) & 0xFu;
        float mx = fmaxf(fmaxf(v0, v1), fmaxf(v2, v3));
        if (mx > t5[4] || m4) {
          int gc = gc0 + it * 4;
          float vv[4] = {v0, v1, v2, v3};
#pragma unroll
          for (int e = 0; e < 4; e++) {
            bool notself = (gc + e != grow);
            if (((m4 >> e) & 1u) && notself) {
              float v = vv[e];
              S += __expf(v * INVT);
              m = fmaxf(m, v);
              ps += v;
              cn += 1.f;
            }
            if (vv[e] > t5[4] && notself) ins5(t5, vv[e]);
          }
        }
      }
    };
    __syncthreads();
    if (wr == 0) dump();
    __syncthreads();
    scan(t5a, mA, SA, psA, cnA, growA, mMA);
    __syncthreads();
    if (wr == 1) dump();
    __syncthreads();
    scan(t5b, mB, SB, psB, cnB, growB, mMB);
  }
  __syncthreads();
  {
    float* slotA = Csm + (size_t)(sq * 128 + srow) * 9;
    float* slotB = Csm + (size_t)(sq * 128 + 64 + srow) * 9;
#pragma unroll
    for (int k = 0; k < 5; k++) { slotA[k] = t5a[k]; slotB[k] = t5b[k]; }
    slotA[5] = mA; slotA[6] = SA; slotA[7] = psA; slotA[8] = cnA;
    slotB[5] = mB; slotB[6] = SB; slotB[7] = psB; slotB[8] = cnB;
  }
  __syncthreads();
  if (t < 128) {
    float t5[5];
    float m = NEGINF, S = 0.f, ps = 0.f, cn = 0.f;
#pragma unroll
    for (int k = 0; k < 5; k++) t5[k] = NEGINF;
#pragma unroll
    for (int q = 0; q < 4; q++) {
      const float* s9 = Csm + (size_t)(q * 128 + t) * 9;
      for (int k = 0; k < 5; k++) {
        float v = s9[k];
        if (!(v > t5[4])) break;
        ins5(t5, v);
      }
      m = fmaxf(m, s9[5]);
      S += s9[6];
      ps += s9[7];
      cn += s9[8];
    }
    store_rec(toppart + ((size_t)(bi * 128 + t) * NPART + part) * 12, t5, m, S, ps, cn);
  }
}

// ---------- wave-parallel merge: one wave per row, lane p owns slot p ----------
// direct-sum form: butterfly is pure adds + fmax (no LSE branching)
__global__ __launch_bounds__(256) void k_merge(const float* __restrict__ toppart,
                                               float* __restrict__ merged,
                                               float* __restrict__ bmax, int nslots) {
  __shared__ float red[4];
  int t = threadIdx.x;
  int lane = t & 63, w = t >> 6;
  int row = blockIdx.x * 4 + w;

  float t5[5], m, S, ps, cn;
  if (lane < nslots) {
    const float* r12 = toppart + ((size_t)row * nslots + lane) * 12;
    float4 a = *(const float4*)r12;
    float4 bq = *(const float4*)(r12 + 4);
    float4 cq = *(const float4*)(r12 + 8);
    t5[0] = a.x; t5[1] = a.y; t5[2] = a.z; t5[3] = a.w; t5[4] = bq.x;
    m = bq.y; S = bq.z; ps = bq.w; cn = cq.x;
  } else {
    t5[0] = t5[1] = t5[2] = t5[3] = t5[4] = NEGINF;
    m = NEGINF; S = 0.f; ps = 0.f; cn = 0.f;
  }
#pragma unroll
  for (int off = 32; off > 0; off >>= 1) {
    float tp[5];
#pragma unroll
    for (int k = 0; k < 5; k++) tp[k] = __shfl_xor(t5[k], off, 64);
    float mp = __shfl_xor(m, off, 64), sp = __shfl_xor(S, off, 64);
    float pp = __shfl_xor(ps, off, 64), cp = __shfl_xor(cn, off, 64);
#pragma unroll
    for (int k = 0; k < 5; k++)
      if (tp[k] > t5[4]) ins5(t5, tp[k]);
    m = fmaxf(m, mp);
    S += sp;
    ps += pp;
    cn += cp;
  }
  if (lane == 0) {
    store_rec(merged + (size_t)row * 12, t5, m, S, ps, cn);
    red[w] = t5[0];
  }
  __syncthreads();
  if (t == 0) bmax[blockIdx.x] = fmaxf(fmaxf(red[0], red[1]), fmaxf(red[2], red[3]));
}

// ---------- per-row loss; Mg from bmax; atomic partial sums; last block writes mean ----------
__global__ __launch_bounds__(256) void k_final(const float* __restrict__ merged,
                                               const float* __restrict__ bmax, int nb,
                                               unsigned* __restrict__ cells,
                                               float* __restrict__ out) {
  __shared__ float red[256];
  int t = threadIdx.x;
  float mg = NEGINF;
  for (int i = t; i < nb; i += 256) mg = fmaxf(mg, bmax[i]);
  red[t] = mg;
  __syncthreads();
  for (int o = 128; o > 0; o >>= 1) {
    if (t < o) red[t] = fmaxf(red[t], red[t + o]);
    __syncthreads();
  }
  float Mg = red[0];
  __syncthreads();

  int row = blockIdx.x * 256 + t;
  const float* m12 = merged + (size_t)row * 12;
  float4 a = *(const float4*)m12;
  float4 bq = *(const float4*)(m12 + 4);
  float4 cq = *(const float4*)(m12 + 8);
  float h = __expf((a.x - Mg) * INVT) + __expf((a.y - Mg) * INVT) +
            __expf((a.z - Mg) * INVT) + __expf((a.w - Mg) * INVT) +
            __expf((bq.x - Mg) * INVT);
  float m = bq.y, S = bq.z, ps = bq.w, cn = cq.x;
  float v = 0.f;
  if (cn > 0.f) {
    float sref = S * __expf(-m * INVT);   // reconstruct row_max-subtracted pos sum
    v = logf(sref + h) - (ps / cn) * INVT;
  }
  red[t] = v;
  __syncthreads();
  for (int o = 128; o > 0; o >>= 1) {
    if (t < o) red[t] += red[t + o];
    __syncthreads();
  }
  if (t == 0) {
    atomicAdd((float*)cells + 1, red[0]);
    __threadfence();
    unsigned done = atomicAdd(&cells[2], 1u);
    if (done == gridDim.x - 1) {
      float total = atomicAdd((float*)cells + 1, 0.0f);  // coherent read
      out[0] = total * (1.0f / (float)BN);
    }
  }
}

extern "C" void kernel_launch(void* const* d_in, const int* in_sizes, int n_in,
                              void* d_out, int out_size, void* d_ws, size_t ws_size,
                              hipStream_t stream) {
  const float* feat = (const float*)d_in[0];
  const int* idx = (const int*)d_in[1];
  float* out = (float*)d_out;
  char* ws = (char*)d_ws;

  _Float16* f16 = (_Float16*)ws;                 // 8 MB (row-major normalized fp16)
  const size_t F16B = (size_t)8 * 1024 * 1024;

  // triangle path: 8 MB + toppart 24 MB + merged 384 KB + bmax 8 KB + cells
  const size_t TRI_TOP = F16B;
  const size_t TRI_MERGED = TRI_TOP + (size_t)BN * 64 * 12 * 4;
  const size_t TRI_BMAX = TRI_MERGED + (size_t)BN * 12 * 4;
  const size_t TRI_CELLS = TRI_BMAX + (size_t)(BN / 4) * 4;
  const size_t TRI_NEED = TRI_CELLS + 64;

  if (ws_size >= TRI_NEED) {
    float* toppart = (float*)(ws + TRI_TOP);
    float* merged = (float*)(ws + TRI_MERGED);
    float* bmax = (float*)(ws + TRI_BMAX);
    unsigned* cells = (unsigned*)(ws + TRI_CELLS);
    k_normalize<<<dim3(BN / 4), dim3(256), 0, stream>>>(feat, f16, cells);
    k_tri<<<dim3(2080), dim3(256), 0, stream>>>(f16, idx, toppart);
    k_merge<<<dim3(BN / 4), dim3(256), 0, stream>>>(toppart, merged, bmax, 64);
    k_final<<<dim3(BN / 256), dim3(256), 0, stream>>>(merged, bmax, BN / 4, cells, out);
  } else {
    // fallback: 8 MB + toppart 4.5 MB + merged + bmax + cells (< 13.2 MB)
    const size_t FB_TOP = F16B;
    const size_t FB_MERGED = FB_TOP + (size_t)BN * NPART * 12 * 4;
    const size_t FB_BMAX = FB_MERGED + (size_t)BN * 12 * 4;
    const size_t FB_CELLS = FB_BMAX + (size_t)(BN / 4) * 4;
    float* toppart = (float*)(ws + FB_TOP);
    float* merged = (float*)(ws + FB_MERGED);
    float* bmax = (float*)(ws + FB_BMAX);
    unsigned* cells = (unsigned*)(ws + FB_CELLS);
    k_normalize<<<dim3(BN / 4), dim3(256), 0, stream>>>(feat, f16, cells);
    k_gemm_fb<<<dim3((BN / 128) * NPART), dim3(256), 0, stream>>>(f16, idx, toppart);
    k_merge<<<dim3(BN / 4), dim3(256), 0, stream>>>(toppart, merged, bmax, NPART);
    k_final<<<dim3(BN / 256), dim3(256), 0, stream>>>(merged, bmax, BN / 4, cells, out);
  }
}